// Round 7
// baseline (549.058 us; speedup 1.0000x reference)
//
#include <hip/hip_runtime.h>
#include <math.h>
#include <stdint.h>

#define NPTS   1048576
#define NLEV   16
#define TPB    256
#define PPT    8                   // points per thread in gather phase
#define CHUNK  (TPB * PPT)         // 2048 points per gather block
#define ROW    35                  // 3 (x) + 16 levels * 2 feats
#define TBL_ENTRIES (1u << 19)

typedef float f4 __attribute__((ext_vector_type(4)));
typedef float f2 __attribute__((ext_vector_type(2)));

struct LevelParams {
    float    resf;
    uint32_t hm;
    uint32_t is_pow2;
    uint32_t use_nt;     // table > 1MB: bypass L1 (nt) on gathers
    uint64_t magic;      // Lemire fastmod: ~0ull/hm + 1 (unused when pow2)
};
struct LPAll { LevelParams lv[NLEV]; };

// Generic path (non-pow2 mod): 8 independent b64 gathers.
__device__ __forceinline__ void hash_gather_generic(
    float xv0, float xv1, float xv2,
    const LevelParams& P, const f2* __restrict__ tbl,
    float& acc0, float& acc1)
{
    const float xs0 = xv0 * P.resf, xs1 = xv1 * P.resf, xs2 = xv2 * P.resf;
    const float f0 = floorf(xs0), f1 = floorf(xs1), f2v = floorf(xs2);
    const float t0 = xs0 - f0, t1 = xs1 - f1, t2 = xs2 - f2v;

    const unsigned a0 = (unsigned)(int)f0;
    const unsigned a1 = a0 + 1u;
    const unsigned b0 = (unsigned)(int)f1 * 2654435761u;
    const unsigned b1 = ((unsigned)(int)f1 + 1u) * 2654435761u;
    const unsigned c0 = (unsigned)(int)f2v * 805459861u;
    const unsigned c1 = ((unsigned)(int)f2v + 1u) * 805459861u;

    const float wa0 = 1.f - t0, wa1 = t0;
    const float wb0 = 1.f - t1, wb1 = t1;
    const float wc0 = 1.f - t2, wc1 = t2;

    const uint32_t hmv = P.hm;
    const uint64_t M   = P.magic;
    const bool     nt  = (P.use_nt != 0);

    unsigned hi[8];
    #pragma unroll
    for (int n = 0; n < 8; ++n) {
        unsigned h = ((n & 1) ? a1 : a0)
                   ^ ((n & 2) ? b1 : b0)
                   ^ ((n & 4) ? c1 : c0);
        uint64_t low = M * (uint64_t)h;           // Lemire fastmod_u32, exact
        hi[n] = (uint32_t)(((__uint128_t)low * hmv) >> 64);
    }
    f2 e[8];
    #pragma unroll
    for (int n = 0; n < 8; ++n)
        e[n] = nt ? __builtin_nontemporal_load(&tbl[hi[n]]) : tbl[hi[n]];

    acc0 = 0.f; acc1 = 0.f;
    #pragma unroll
    for (int n = 0; n < 8; ++n) {
        float w = (((n & 1) ? wa1 : wa0) * ((n & 2) ? wb1 : wb0))
                  * ((n & 4) ? wc1 : wc0);
        acc0 = fmaf(e[n].x, w, acc0);
        acc1 = fmaf(e[n].y, w, acc1);
    }
}

// Pow2 path: PRIME[0]==1 => for each (dim1,dim2) combo, the two dim-0
// corners hash to {h, h^1} when xi0 is even -> one aligned b128 covers both.
// 4 primary paired loads always; 4 secondary loads only in the exec-masked
// odd-xi0 branch (~50% of lanes) => ~6 requests/point instead of 8.
__device__ __forceinline__ void hash_gather_pow2(
    float xv0, float xv1, float xv2,
    const LevelParams& P, const f4* __restrict__ tbl4,
    float& acc0, float& acc1)
{
    const float xs0 = xv0 * P.resf, xs1 = xv1 * P.resf, xs2 = xv2 * P.resf;
    const float f0 = floorf(xs0), f1 = floorf(xs1), f2v = floorf(xs2);
    const float t0 = xs0 - f0, t1 = xs1 - f1, t2 = xs2 - f2v;

    const unsigned a0 = (unsigned)(int)f0;
    const unsigned a1 = a0 + 1u;
    const unsigned b0 = (unsigned)(int)f1 * 2654435761u;
    const unsigned b1 = ((unsigned)(int)f1 + 1u) * 2654435761u;
    const unsigned c0 = (unsigned)(int)f2v * 805459861u;
    const unsigned c1 = ((unsigned)(int)f2v + 1u) * 805459861u;

    const float wa0 = 1.f - t0, wa1 = t0;
    const float wb0 = 1.f - t1, wb1 = t1;
    const float wc0 = 1.f - t2, wc1 = t2;

    const uint32_t mask = P.hm - 1u;
    const bool     nt   = (P.use_nt != 0);     // uniform per block

    unsigned s[4]; float wp[4];
    s[0] = b0 ^ c0;  wp[0] = wb0 * wc0;
    s[1] = b1 ^ c0;  wp[1] = wb1 * wc0;
    s[2] = b0 ^ c1;  wp[2] = wb0 * wc1;
    s[3] = b1 ^ c1;  wp[3] = wb1 * wc1;

    unsigned hl[4], hh[4];
    #pragma unroll
    for (int j = 0; j < 4; ++j) {
        hl[j] = (a0 ^ s[j]) & mask;
        hh[j] = (a1 ^ s[j]) & mask;
    }

    f4 q[4];
    #pragma unroll
    for (int j = 0; j < 4; ++j)
        q[j] = nt ? __builtin_nontemporal_load(&tbl4[hl[j] >> 1])
                  : tbl4[hl[j] >> 1];

    // when xi0 even: hh == hl^1, the other half of q[j] already has it
    f4 qh[4];
    #pragma unroll
    for (int j = 0; j < 4; ++j) qh[j] = q[j];

    if (a0 & 1u) {                             // divergent, exec-masked loads
        #pragma unroll
        for (int j = 0; j < 4; ++j)
            qh[j] = nt ? __builtin_nontemporal_load(&tbl4[hh[j] >> 1])
                       : tbl4[hh[j] >> 1];
    }

    acc0 = 0.f; acc1 = 0.f;
    #pragma unroll
    for (int j = 0; j < 4; ++j) {
        const bool sl = (hl[j] & 1u);
        const bool sh = (hh[j] & 1u);
        const float elo0 = sl ? q[j].z  : q[j].x;
        const float elo1 = sl ? q[j].w  : q[j].y;
        const float ehi0 = sh ? qh[j].z : qh[j].x;
        const float ehi1 = sh ? qh[j].w : qh[j].y;
        const float wl = wa0 * wp[j];
        const float wh = wa1 * wp[j];
        acc0 = fmaf(elo0, wl, acc0);
        acc1 = fmaf(elo1, wl, acc1);
        acc0 = fmaf(ehi0, wh, acc0);
        acc1 = fmaf(ehi1, wh, acc1);
    }
}

// Phase 1: one block = (level, 2048-point chunk); blockIdx%8 -> level ->
// XCD-pinned so each level's <=4MB table is L2-resident. No LDS, no barriers.
__global__ __launch_bounds__(TPB)
void hashgrid_gather(const float* __restrict__ x,
                     const float* __restrict__ tables,
                     float* __restrict__ ws,
                     LPAll lp, int base)
{
    const int tid = threadIdx.x;
    const int lvl = base + (blockIdx.x & 7);
    const int p0  = (blockIdx.x >> 3) * CHUNK;

    const LevelParams P   = lp.lv[lvl];
    const float*      tb  = tables + (size_t)lvl * TBL_ENTRIES * 2;
    const float*      xp  = x + (size_t)p0 * 3;
    f2* wrow = (f2*)ws + (size_t)lvl * NPTS + p0;

    if (P.is_pow2) {
        const f4* tbl4 = (const f4*)tb;
        #pragma unroll
        for (int k = 0; k < PPT; ++k) {
            const int pi = tid + k * TPB;
            const float xv0 = __builtin_nontemporal_load(&xp[pi * 3 + 0]);
            const float xv1 = __builtin_nontemporal_load(&xp[pi * 3 + 1]);
            const float xv2 = __builtin_nontemporal_load(&xp[pi * 3 + 2]);
            float acc0, acc1;
            hash_gather_pow2(xv0, xv1, xv2, P, tbl4, acc0, acc1);
            f2 v; v.x = acc0; v.y = acc1;
            __builtin_nontemporal_store(v, &wrow[pi]);
        }
    } else {
        const f2* tbl = (const f2*)tb;
        #pragma unroll
        for (int k = 0; k < PPT; ++k) {
            const int pi = tid + k * TPB;
            const float xv0 = __builtin_nontemporal_load(&xp[pi * 3 + 0]);
            const float xv1 = __builtin_nontemporal_load(&xp[pi * 3 + 1]);
            const float xv2 = __builtin_nontemporal_load(&xp[pi * 3 + 2]);
            float acc0, acc1;
            hash_gather_generic(xv0, xv1, xv2, P, tbl, acc0, acc1);
            f2 v; v.x = acc0; v.y = acc1;
            __builtin_nontemporal_store(v, &wrow[pi]);
        }
    }
}

// Phase 2: streaming interleave ws (level-major) + x -> row-major out,
// flushed as full float4 lines.
__global__ __launch_bounds__(TPB)
void hashgrid_interleave(const float* __restrict__ x,
                         const float* __restrict__ ws,
                         float* __restrict__ out)
{
    __shared__ float srow[TPB * ROW];
    const int tid = threadIdx.x;
    const int p0  = blockIdx.x * TPB;

    const float* xblk = x + (size_t)p0 * 3;
    #pragma unroll
    for (int j = 0; j < 3; ++j) {
        int idx = tid + j * TPB;
        int p = idx / 3, c = idx - p * 3;
        srow[p * ROW + c] = __builtin_nontemporal_load(&xblk[idx]);
    }
    const f2* wsv = (const f2*)ws;
    #pragma unroll
    for (int l = 0; l < NLEV; ++l) {
        f2 v = __builtin_nontemporal_load(&wsv[(size_t)l * NPTS + p0 + tid]);
        srow[tid * ROW + 3 + 2 * l] = v.x;
        srow[tid * ROW + 4 + 2 * l] = v.y;
    }
    __syncthreads();

    f4*       outv = (f4*)(out + (size_t)p0 * ROW);
    const f4* sv   = (const f4*)srow;
    for (int j = tid; j < (TPB * ROW) / 4; j += TPB)
        __builtin_nontemporal_store(sv[j], &outv[j]);
}

// Fallback (ws too small): direct scattered-store path.
__global__ __launch_bounds__(TPB)
void hashgrid_lvl(const float* __restrict__ x,
                  const float* __restrict__ tables,
                  float* __restrict__ out,
                  LPAll lp, int base)
{
    const int tid = threadIdx.x;
    const int lvl = base + (blockIdx.x & 7);
    const int p0  = (blockIdx.x >> 3) * TPB;

    const float* xp = x + (size_t)p0 * 3;
    const float xv0 = xp[tid * 3 + 0];
    const float xv1 = xp[tid * 3 + 1];
    const float xv2 = xp[tid * 3 + 2];

    const LevelParams P  = lp.lv[lvl];
    const float*      tb = tables + (size_t)lvl * TBL_ENTRIES * 2;
    float acc0, acc1;
    if (P.is_pow2) hash_gather_pow2(xv0, xv1, xv2, P, (const f4*)tb, acc0, acc1);
    else           hash_gather_generic(xv0, xv1, xv2, P, (const f2*)tb, acc0, acc1);

    float* orow = out + (size_t)(p0 + tid) * ROW;
    __builtin_nontemporal_store(acc0, &orow[3 + 2 * lvl]);
    __builtin_nontemporal_store(acc1, &orow[4 + 2 * lvl]);
    if (lvl == 0) {
        __builtin_nontemporal_store(xv0, &orow[0]);
        __builtin_nontemporal_store(xv1, &orow[1]);
        __builtin_nontemporal_store(xv2, &orow[2]);
    }
}

extern "C" void kernel_launch(void* const* d_in, const int* in_sizes, int n_in,
                              void* d_out, int out_size, void* d_ws, size_t ws_size,
                              hipStream_t stream)
{
    const float* x      = (const float*)d_in[0];
    const float* tables = (const float*)d_in[1];
    float*       out    = (float*)d_out;

    // Host-side level params with system libm -> bit-identical to CPython math.
    LPAll lp;
    const double beta = exp((log(2048.0) - log(16.0)) / 15.0);
    for (int i = 0; i < NLEV; ++i) {
        double r = floor(16.0 * pow(beta, (double)i));
        double h3 = r * r * r;                 // res^3, exact in double
        uint32_t hm = (h3 < (double)(1u << 19)) ? (uint32_t)h3 : (1u << 19);
        lp.lv[i].resf    = (float)r;
        lp.lv[i].hm      = hm;
        lp.lv[i].is_pow2 = ((hm & (hm - 1u)) == 0u) ? 1u : 0u;
        lp.lv[i].use_nt  = ((size_t)hm * 8 > (1u << 20)) ? 1u : 0u;
        lp.lv[i].magic   = lp.lv[i].is_pow2 ? 0ull : (~0ull / hm + 1ull);
    }

    const size_t ws_need = (size_t)NLEV * NPTS * 2 * sizeof(float);  // 128 MB
    if (ws_size >= ws_need) {
        const int gblocks = 8 * (NPTS / CHUNK);   // 8 levels x 512 chunks
        hashgrid_gather<<<gblocks, TPB, 0, stream>>>(x, tables, (float*)d_ws, lp, 0);
        hashgrid_gather<<<gblocks, TPB, 0, stream>>>(x, tables, (float*)d_ws, lp, 8);
        hashgrid_interleave<<<NPTS / TPB, TPB, 0, stream>>>(x, (const float*)d_ws, out);
    } else {
        const int nblocks = 8 * (NPTS / TPB);
        hashgrid_lvl<<<nblocks, TPB, 0, stream>>>(x, tables, out, lp, 0);
        hashgrid_lvl<<<nblocks, TPB, 0, stream>>>(x, tables, out, lp, 8);
    }
}

// Round 8
// 545.130 us; speedup vs baseline: 1.0072x; 1.0072x over previous
//
#include <hip/hip_runtime.h>
#include <math.h>
#include <stdint.h>

#define NPTS   1048576
#define NLEV   16
#define TPB    256
#define PPT    8                   // points per thread in gather phase
#define CHUNK  (TPB * PPT)         // 2048 points per gather block
#define ROW    35                  // 3 (x) + 16 levels * 2 feats
#define TBL_ENTRIES (1u << 19)

typedef float f4 __attribute__((ext_vector_type(4)));
typedef float f2 __attribute__((ext_vector_type(2)));

struct LevelParams {
    float    resf;
    uint32_t hm;
    uint32_t is_pow2;
    uint32_t pad;
    uint64_t magic;      // Lemire fastmod: ~0ull/hm + 1 (unused when pow2)
};
struct LPAll { LevelParams lv[NLEV]; };

// Generic path (non-pow2 mod): 8 independent b64 gathers (round-6 proven).
__device__ __forceinline__ void hash_gather_generic(
    float xv0, float xv1, float xv2,
    const LevelParams& P, const f2* __restrict__ tbl,
    float& acc0, float& acc1)
{
    const float xs0 = xv0 * P.resf, xs1 = xv1 * P.resf, xs2 = xv2 * P.resf;
    const float f0 = floorf(xs0), f1 = floorf(xs1), f2v = floorf(xs2);
    const float t0 = xs0 - f0, t1 = xs1 - f1, t2 = xs2 - f2v;

    const unsigned a0 = (unsigned)(int)f0;
    const unsigned a1 = a0 + 1u;
    const unsigned b0 = (unsigned)(int)f1 * 2654435761u;
    const unsigned b1 = ((unsigned)(int)f1 + 1u) * 2654435761u;
    const unsigned c0 = (unsigned)(int)f2v * 805459861u;
    const unsigned c1 = ((unsigned)(int)f2v + 1u) * 805459861u;

    const float wa0 = 1.f - t0, wa1 = t0;
    const float wb0 = 1.f - t1, wb1 = t1;
    const float wc0 = 1.f - t2, wc1 = t2;

    const uint32_t hmv = P.hm;
    const uint64_t M   = P.magic;

    unsigned hi[8];
    #pragma unroll
    for (int n = 0; n < 8; ++n) {
        unsigned h = ((n & 1) ? a1 : a0)
                   ^ ((n & 2) ? b1 : b0)
                   ^ ((n & 4) ? c1 : c0);
        uint64_t low = M * (uint64_t)h;           // Lemire fastmod_u32, exact
        hi[n] = (uint32_t)(((__uint128_t)low * hmv) >> 64);
    }
    f2 e[8];
    #pragma unroll
    for (int n = 0; n < 8; ++n)
        e[n] = tbl[hi[n]];

    acc0 = 0.f; acc1 = 0.f;
    #pragma unroll
    for (int n = 0; n < 8; ++n) {
        float w = (((n & 1) ? wa1 : wa0) * ((n & 2) ? wb1 : wb0))
                  * ((n & 4) ? wc1 : wc0);
        acc0 = fmaf(e[n].x, w, acc0);
        acc1 = fmaf(e[n].y, w, acc1);
    }
}

// Pow2 path: PRIME[0]==1 => the aligned 16B block at (g>>1) holds entries
// {g&~1, g|1}, i.e. BOTH dim-0 corners when a0 is even (h_high = h_low^1).
// Corner a0's entry ALWAYS comes from the primary block (select by g&1).
// Only odd-a0 lanes need a secondary block for corner a0+1.
// KEY vs round 7: secondary regs are zero-init (no dep on primaries), masked
// loads issue before any primary consumption -> all 8 loads in flight at once.
__device__ __forceinline__ void hash_gather_pow2(
    float xv0, float xv1, float xv2,
    const LevelParams& P, const f4* __restrict__ tbl4,
    float& acc0, float& acc1)
{
    const float xs0 = xv0 * P.resf, xs1 = xv1 * P.resf, xs2 = xv2 * P.resf;
    const float f0 = floorf(xs0), f1 = floorf(xs1), f2v = floorf(xs2);
    const float t0 = xs0 - f0, t1 = xs1 - f1, t2 = xs2 - f2v;

    const unsigned a0 = (unsigned)(int)f0;
    const unsigned a1 = a0 + 1u;
    const unsigned b0 = (unsigned)(int)f1 * 2654435761u;
    const unsigned b1 = ((unsigned)(int)f1 + 1u) * 2654435761u;
    const unsigned c0 = (unsigned)(int)f2v * 805459861u;
    const unsigned c1 = ((unsigned)(int)f2v + 1u) * 805459861u;

    const float wa0 = 1.f - t0, wa1 = t0;
    const float wb0 = 1.f - t1, wb1 = t1;
    const float wc0 = 1.f - t2, wc1 = t2;

    const uint32_t mask = P.hm - 1u;

    unsigned s[4]; float wp[4];
    s[0] = b0 ^ c0;  wp[0] = wb0 * wc0;
    s[1] = b1 ^ c0;  wp[1] = wb1 * wc0;
    s[2] = b0 ^ c1;  wp[2] = wb0 * wc1;
    s[3] = b1 ^ c1;  wp[3] = wb1 * wc1;

    unsigned gl[4], gh[4];
    #pragma unroll
    for (int j = 0; j < 4; ++j) {
        gl[j] = (a0 ^ s[j]) & mask;
        gh[j] = (a1 ^ s[j]) & mask;
    }

    // zero-init secondaries FIRST: no dependency on primary loads
    f4 r[4] = {};

    f4 q[4];
    #pragma unroll
    for (int j = 0; j < 4; ++j)
        q[j] = tbl4[gl[j] >> 1];               // primary: covers gl and gl^1

    const bool odd = (a0 & 1u) != 0u;
    if (odd) {                                  // exec-masked, ~50% of lanes;
        #pragma unroll                          // independent of q -> issues
        for (int j = 0; j < 4; ++j)             // back-to-back with primaries
            r[j] = tbl4[gh[j] >> 1];
    }

    acc0 = 0.f; acc1 = 0.f;
    #pragma unroll
    for (int j = 0; j < 4; ++j) {
        const bool sl = (gl[j] & 1u) != 0u;
        const bool sh = (gh[j] & 1u) != 0u;
        // corner a0: always in primary block (even a0: trivially; odd a0:
        // gl's own block still contains entry gl)
        const float elo0 = sl ? q[j].z : q[j].x;
        const float elo1 = sl ? q[j].w : q[j].y;
        // corner a0+1: even a0 -> other half of primary; odd a0 -> secondary
        const f4 src = odd ? r[j] : q[j];
        const float ehi0 = sh ? src.z : src.x;
        const float ehi1 = sh ? src.w : src.y;
        const float wl = wa0 * wp[j];
        const float wh = wa1 * wp[j];
        acc0 = fmaf(elo0, wl, acc0);
        acc1 = fmaf(elo1, wl, acc1);
        acc0 = fmaf(ehi0, wh, acc0);
        acc1 = fmaf(ehi1, wh, acc1);
    }
}

// Phase 1: one block = (level, 2048-point chunk); blockIdx%8 -> level ->
// XCD-pinned so each level's <=4MB table is L2-resident. No LDS, no barriers.
__global__ __launch_bounds__(TPB)
void hashgrid_gather(const float* __restrict__ x,
                     const float* __restrict__ tables,
                     float* __restrict__ ws,
                     LPAll lp, int base)
{
    const int tid = threadIdx.x;
    const int lvl = base + (blockIdx.x & 7);
    const int p0  = (blockIdx.x >> 3) * CHUNK;

    const LevelParams P   = lp.lv[lvl];
    const float*      tb  = tables + (size_t)lvl * TBL_ENTRIES * 2;
    const float*      xp  = x + (size_t)p0 * 3;
    f2* wrow = (f2*)ws + (size_t)lvl * NPTS + p0;

    if (P.is_pow2) {
        const f4* tbl4 = (const f4*)tb;
        #pragma unroll
        for (int k = 0; k < PPT; ++k) {
            const int pi = tid + k * TPB;
            const float xv0 = __builtin_nontemporal_load(&xp[pi * 3 + 0]);
            const float xv1 = __builtin_nontemporal_load(&xp[pi * 3 + 1]);
            const float xv2 = __builtin_nontemporal_load(&xp[pi * 3 + 2]);
            float acc0, acc1;
            hash_gather_pow2(xv0, xv1, xv2, P, tbl4, acc0, acc1);
            f2 v; v.x = acc0; v.y = acc1;
            __builtin_nontemporal_store(v, &wrow[pi]);
        }
    } else {
        const f2* tbl = (const f2*)tb;
        #pragma unroll
        for (int k = 0; k < PPT; ++k) {
            const int pi = tid + k * TPB;
            const float xv0 = __builtin_nontemporal_load(&xp[pi * 3 + 0]);
            const float xv1 = __builtin_nontemporal_load(&xp[pi * 3 + 1]);
            const float xv2 = __builtin_nontemporal_load(&xp[pi * 3 + 2]);
            float acc0, acc1;
            hash_gather_generic(xv0, xv1, xv2, P, tbl, acc0, acc1);
            f2 v; v.x = acc0; v.y = acc1;
            __builtin_nontemporal_store(v, &wrow[pi]);
        }
    }
}

// Phase 2: streaming interleave ws (level-major) + x -> row-major out,
// flushed as full float4 lines.
__global__ __launch_bounds__(TPB)
void hashgrid_interleave(const float* __restrict__ x,
                         const float* __restrict__ ws,
                         float* __restrict__ out)
{
    __shared__ float srow[TPB * ROW];
    const int tid = threadIdx.x;
    const int p0  = blockIdx.x * TPB;

    const float* xblk = x + (size_t)p0 * 3;
    #pragma unroll
    for (int j = 0; j < 3; ++j) {
        int idx = tid + j * TPB;
        int p = idx / 3, c = idx - p * 3;
        srow[p * ROW + c] = __builtin_nontemporal_load(&xblk[idx]);
    }
    const f2* wsv = (const f2*)ws;
    #pragma unroll
    for (int l = 0; l < NLEV; ++l) {
        f2 v = __builtin_nontemporal_load(&wsv[(size_t)l * NPTS + p0 + tid]);
        srow[tid * ROW + 3 + 2 * l] = v.x;
        srow[tid * ROW + 4 + 2 * l] = v.y;
    }
    __syncthreads();

    f4*       outv = (f4*)(out + (size_t)p0 * ROW);
    const f4* sv   = (const f4*)srow;
    for (int j = tid; j < (TPB * ROW) / 4; j += TPB)
        __builtin_nontemporal_store(sv[j], &outv[j]);
}

// Fallback (ws too small): direct scattered-store path.
__global__ __launch_bounds__(TPB)
void hashgrid_lvl(const float* __restrict__ x,
                  const float* __restrict__ tables,
                  float* __restrict__ out,
                  LPAll lp, int base)
{
    const int tid = threadIdx.x;
    const int lvl = base + (blockIdx.x & 7);
    const int p0  = (blockIdx.x >> 3) * TPB;

    const float* xp = x + (size_t)p0 * 3;
    const float xv0 = xp[tid * 3 + 0];
    const float xv1 = xp[tid * 3 + 1];
    const float xv2 = xp[tid * 3 + 2];

    const LevelParams P  = lp.lv[lvl];
    const float*      tb = tables + (size_t)lvl * TBL_ENTRIES * 2;
    float acc0, acc1;
    if (P.is_pow2) hash_gather_pow2(xv0, xv1, xv2, P, (const f4*)tb, acc0, acc1);
    else           hash_gather_generic(xv0, xv1, xv2, P, (const f2*)tb, acc0, acc1);

    float* orow = out + (size_t)(p0 + tid) * ROW;
    __builtin_nontemporal_store(acc0, &orow[3 + 2 * lvl]);
    __builtin_nontemporal_store(acc1, &orow[4 + 2 * lvl]);
    if (lvl == 0) {
        __builtin_nontemporal_store(xv0, &orow[0]);
        __builtin_nontemporal_store(xv1, &orow[1]);
        __builtin_nontemporal_store(xv2, &orow[2]);
    }
}

extern "C" void kernel_launch(void* const* d_in, const int* in_sizes, int n_in,
                              void* d_out, int out_size, void* d_ws, size_t ws_size,
                              hipStream_t stream)
{
    const float* x      = (const float*)d_in[0];
    const float* tables = (const float*)d_in[1];
    float*       out    = (float*)d_out;

    // Host-side level params with system libm -> bit-identical to CPython math.
    LPAll lp;
    const double beta = exp((log(2048.0) - log(16.0)) / 15.0);
    for (int i = 0; i < NLEV; ++i) {
        double r = floor(16.0 * pow(beta, (double)i));
        double h3 = r * r * r;                 // res^3, exact in double
        uint32_t hm = (h3 < (double)(1u << 19)) ? (uint32_t)h3 : (1u << 19);
        lp.lv[i].resf    = (float)r;
        lp.lv[i].hm      = hm;
        lp.lv[i].is_pow2 = ((hm & (hm - 1u)) == 0u) ? 1u : 0u;
        lp.lv[i].pad     = 0;
        lp.lv[i].magic   = lp.lv[i].is_pow2 ? 0ull : (~0ull / hm + 1ull);
    }

    const size_t ws_need = (size_t)NLEV * NPTS * 2 * sizeof(float);  // 128 MB
    if (ws_size >= ws_need) {
        const int gblocks = 8 * (NPTS / CHUNK);   // 8 levels x 512 chunks
        hashgrid_gather<<<gblocks, TPB, 0, stream>>>(x, tables, (float*)d_ws, lp, 0);
        hashgrid_gather<<<gblocks, TPB, 0, stream>>>(x, tables, (float*)d_ws, lp, 8);
        hashgrid_interleave<<<NPTS / TPB, TPB, 0, stream>>>(x, (const float*)d_ws, out);
    } else {
        const int nblocks = 8 * (NPTS / TPB);
        hashgrid_lvl<<<nblocks, TPB, 0, stream>>>(x, tables, out, lp, 0);
        hashgrid_lvl<<<nblocks, TPB, 0, stream>>>(x, tables, out, lp, 8);
    }
}

// Round 9
// 476.322 us; speedup vs baseline: 1.1527x; 1.1445x over previous
//
#include <hip/hip_runtime.h>
#include <math.h>
#include <stdint.h>

#define NPTS   1048576
#define NLEV   16
#define TPB    256
#define PPT    8                   // points per thread in gather phase
#define CHUNK  (TPB * PPT)         // 2048 points per gather block
#define ROW    35                  // 3 (x) + 16 levels * 2 feats
#define TBL_ENTRIES (1u << 19)

typedef float f4 __attribute__((ext_vector_type(4)));
typedef float f2 __attribute__((ext_vector_type(2)));

struct LevelParams {
    float    resf;
    uint32_t hm;
    uint32_t is_pow2;
    uint32_t pad;
    uint64_t magic;      // Lemire fastmod: ~0ull/hm + 1 (unused when pow2)
};
struct LPAll { LevelParams lv[NLEV]; };

// Compute the 8 hash indices + weights for one point (no loads).
__device__ __forceinline__ void hash_calc(
    float xv0, float xv1, float xv2, const LevelParams& P,
    unsigned (&hi)[8], float (&w)[8])
{
    const float xs0 = xv0 * P.resf, xs1 = xv1 * P.resf, xs2 = xv2 * P.resf;
    const float f0 = floorf(xs0), f1 = floorf(xs1), f2v = floorf(xs2);
    const float t0 = xs0 - f0, t1 = xs1 - f1, t2 = xs2 - f2v;

    const unsigned a0 = (unsigned)(int)f0;
    const unsigned a1 = a0 + 1u;
    const unsigned b0 = (unsigned)(int)f1 * 2654435761u;
    const unsigned b1 = ((unsigned)(int)f1 + 1u) * 2654435761u;
    const unsigned c0 = (unsigned)(int)f2v * 805459861u;
    const unsigned c1 = ((unsigned)(int)f2v + 1u) * 805459861u;

    const float wa0 = 1.f - t0, wa1 = t0;
    const float wb0 = 1.f - t1, wb1 = t1;
    const float wc0 = 1.f - t2, wc1 = t2;

    const uint32_t hmv  = P.hm;
    const uint32_t mask = hmv - 1u;
    const uint64_t M    = P.magic;
    const bool     p2   = (P.is_pow2 != 0);   // uniform per block

    #pragma unroll
    for (int n = 0; n < 8; ++n) {
        unsigned h = ((n & 1) ? a1 : a0)
                   ^ ((n & 2) ? b1 : b0)
                   ^ ((n & 4) ? c1 : c0);
        if (p2) {
            hi[n] = h & mask;
        } else {
            uint64_t low = M * (uint64_t)h;       // Lemire fastmod_u32, exact
            hi[n] = (uint32_t)(((__uint128_t)low * hmv) >> 64);
        }
        w[n] = (((n & 1) ? wa1 : wa0) * ((n & 2) ? wb1 : wb0))
               * ((n & 4) ? wc1 : wc0);
    }
}

// Phase 1: one block = (level, 2048-point chunk); blockIdx%8 -> level ->
// XCD-pinned so each level's <=4MB table is L2-resident. No LDS, no barriers.
// Software-pipelined 2 points deep: 16 gathers in flight, one drain per pair.
__global__ __launch_bounds__(TPB)
void hashgrid_gather(const float* __restrict__ x,
                     const float* __restrict__ tables,
                     float* __restrict__ ws,
                     LPAll lp, int base)
{
    const int tid = threadIdx.x;
    const int lvl = base + (blockIdx.x & 7);
    const int p0  = (blockIdx.x >> 3) * CHUNK;

    const LevelParams P   = lp.lv[lvl];
    const f2*         tbl = (const f2*)(tables + (size_t)lvl * TBL_ENTRIES * 2);
    const float*      xp  = x + (size_t)p0 * 3;
    f2* wrow = (f2*)ws + (size_t)lvl * NPTS + p0;

    #pragma unroll
    for (int kk = 0; kk < PPT; kk += 2) {
        const int piA = tid + kk * TPB;
        const int piB = piA + TPB;

        const float xa0 = __builtin_nontemporal_load(&xp[piA * 3 + 0]);
        const float xa1 = __builtin_nontemporal_load(&xp[piA * 3 + 1]);
        const float xa2 = __builtin_nontemporal_load(&xp[piA * 3 + 2]);
        const float xb0 = __builtin_nontemporal_load(&xp[piB * 3 + 0]);
        const float xb1 = __builtin_nontemporal_load(&xp[piB * 3 + 1]);
        const float xb2 = __builtin_nontemporal_load(&xp[piB * 3 + 2]);

        unsigned hA[8]; float wA[8];
        unsigned hB[8]; float wB[8];
        hash_calc(xa0, xa1, xa2, P, hA, wA);
        hash_calc(xb0, xb1, xb2, P, hB, wB);

        // issue all 16 independent gathers back-to-back, then consume:
        // compiler can wait with vmcnt(8) before the A-consume, keeping
        // B's 8 loads in flight across it.
        f2 eA[8], eB[8];
        #pragma unroll
        for (int n = 0; n < 8; ++n) eA[n] = tbl[hA[n]];
        #pragma unroll
        for (int n = 0; n < 8; ++n) eB[n] = tbl[hB[n]];

        float accA0 = 0.f, accA1 = 0.f, accB0 = 0.f, accB1 = 0.f;
        #pragma unroll
        for (int n = 0; n < 8; ++n) {
            accA0 = fmaf(eA[n].x, wA[n], accA0);
            accA1 = fmaf(eA[n].y, wA[n], accA1);
        }
        #pragma unroll
        for (int n = 0; n < 8; ++n) {
            accB0 = fmaf(eB[n].x, wB[n], accB0);
            accB1 = fmaf(eB[n].y, wB[n], accB1);
        }

        f2 vA; vA.x = accA0; vA.y = accA1;
        f2 vB; vB.x = accB0; vB.y = accB1;
        __builtin_nontemporal_store(vA, &wrow[piA]);
        __builtin_nontemporal_store(vB, &wrow[piB]);
    }
}

// Phase 2: streaming interleave ws (level-major) + x -> row-major out,
// flushed as full float4 lines.
__global__ __launch_bounds__(TPB)
void hashgrid_interleave(const float* __restrict__ x,
                         const float* __restrict__ ws,
                         float* __restrict__ out)
{
    __shared__ float srow[TPB * ROW];
    const int tid = threadIdx.x;
    const int p0  = blockIdx.x * TPB;

    const float* xblk = x + (size_t)p0 * 3;
    #pragma unroll
    for (int j = 0; j < 3; ++j) {
        int idx = tid + j * TPB;
        int p = idx / 3, c = idx - p * 3;
        srow[p * ROW + c] = __builtin_nontemporal_load(&xblk[idx]);
    }
    const f2* wsv = (const f2*)ws;
    #pragma unroll
    for (int l = 0; l < NLEV; ++l) {
        f2 v = __builtin_nontemporal_load(&wsv[(size_t)l * NPTS + p0 + tid]);
        srow[tid * ROW + 3 + 2 * l] = v.x;
        srow[tid * ROW + 4 + 2 * l] = v.y;
    }
    __syncthreads();

    f4*       outv = (f4*)(out + (size_t)p0 * ROW);
    const f4* sv   = (const f4*)srow;
    for (int j = tid; j < (TPB * ROW) / 4; j += TPB)
        __builtin_nontemporal_store(sv[j], &outv[j]);
}

// Fallback (ws too small): direct scattered-store path.
__global__ __launch_bounds__(TPB)
void hashgrid_lvl(const float* __restrict__ x,
                  const float* __restrict__ tables,
                  float* __restrict__ out,
                  LPAll lp, int base)
{
    const int tid = threadIdx.x;
    const int lvl = base + (blockIdx.x & 7);
    const int p0  = (blockIdx.x >> 3) * TPB;

    const float* xp = x + (size_t)p0 * 3;
    const float xv0 = xp[tid * 3 + 0];
    const float xv1 = xp[tid * 3 + 1];
    const float xv2 = xp[tid * 3 + 2];

    const LevelParams P   = lp.lv[lvl];
    const f2*         tbl = (const f2*)(tables + (size_t)lvl * TBL_ENTRIES * 2);

    unsigned hi[8]; float w[8];
    hash_calc(xv0, xv1, xv2, P, hi, w);
    float acc0 = 0.f, acc1 = 0.f;
    #pragma unroll
    for (int n = 0; n < 8; ++n) {
        f2 e = tbl[hi[n]];
        acc0 = fmaf(e.x, w[n], acc0);
        acc1 = fmaf(e.y, w[n], acc1);
    }

    float* orow = out + (size_t)(p0 + tid) * ROW;
    __builtin_nontemporal_store(acc0, &orow[3 + 2 * lvl]);
    __builtin_nontemporal_store(acc1, &orow[4 + 2 * lvl]);
    if (lvl == 0) {
        __builtin_nontemporal_store(xv0, &orow[0]);
        __builtin_nontemporal_store(xv1, &orow[1]);
        __builtin_nontemporal_store(xv2, &orow[2]);
    }
}

extern "C" void kernel_launch(void* const* d_in, const int* in_sizes, int n_in,
                              void* d_out, int out_size, void* d_ws, size_t ws_size,
                              hipStream_t stream)
{
    const float* x      = (const float*)d_in[0];
    const float* tables = (const float*)d_in[1];
    float*       out    = (float*)d_out;

    // Host-side level params with system libm -> bit-identical to CPython math.
    LPAll lp;
    const double beta = exp((log(2048.0) - log(16.0)) / 15.0);
    for (int i = 0; i < NLEV; ++i) {
        double r = floor(16.0 * pow(beta, (double)i));
        double h3 = r * r * r;                 // res^3, exact in double
        uint32_t hm = (h3 < (double)(1u << 19)) ? (uint32_t)h3 : (1u << 19);
        lp.lv[i].resf    = (float)r;
        lp.lv[i].hm      = hm;
        lp.lv[i].is_pow2 = ((hm & (hm - 1u)) == 0u) ? 1u : 0u;
        lp.lv[i].pad     = 0;
        lp.lv[i].magic   = lp.lv[i].is_pow2 ? 0ull : (~0ull / hm + 1ull);
    }

    const size_t ws_need = (size_t)NLEV * NPTS * 2 * sizeof(float);  // 128 MB
    if (ws_size >= ws_need) {
        const int gblocks = 8 * (NPTS / CHUNK);   // 8 levels x 512 chunks
        hashgrid_gather<<<gblocks, TPB, 0, stream>>>(x, tables, (float*)d_ws, lp, 0);
        hashgrid_gather<<<gblocks, TPB, 0, stream>>>(x, tables, (float*)d_ws, lp, 8);
        hashgrid_interleave<<<NPTS / TPB, TPB, 0, stream>>>(x, (const float*)d_ws, out);
    } else {
        const int nblocks = 8 * (NPTS / TPB);
        hashgrid_lvl<<<nblocks, TPB, 0, stream>>>(x, tables, out, lp, 0);
        hashgrid_lvl<<<nblocks, TPB, 0, stream>>>(x, tables, out, lp, 8);
    }
}

// Round 10
// 438.622 us; speedup vs baseline: 1.2518x; 1.0860x over previous
//
#include <hip/hip_runtime.h>
#include <math.h>
#include <stdint.h>

#define NPTS   1048576
#define NLEV   16
#define TPB    256
#define ROW    35                  // 3 (x) + 16 levels * 2 feats
#define TBL_ENTRIES (1u << 19)

typedef float f4 __attribute__((ext_vector_type(4)));
typedef float f2 __attribute__((ext_vector_type(2)));

struct LevelParams {
    float    resf;
    uint32_t hm;
    uint32_t is_pow2;
    uint32_t pad;
    uint64_t magic;      // Lemire fastmod: ~0ull/hm + 1 (unused when pow2)
};
struct LPAll { LevelParams lv[NLEV]; };

// Compute the 8 hash indices + weights for one point (no loads).
__device__ __forceinline__ void hash_calc(
    float xv0, float xv1, float xv2, const LevelParams& P,
    unsigned (&hi)[8], float (&w)[8])
{
    const float xs0 = xv0 * P.resf, xs1 = xv1 * P.resf, xs2 = xv2 * P.resf;
    const float f0 = floorf(xs0), f1 = floorf(xs1), f2v = floorf(xs2);
    const float t0 = xs0 - f0, t1 = xs1 - f1, t2 = xs2 - f2v;

    const unsigned a0 = (unsigned)(int)f0;
    const unsigned a1 = a0 + 1u;
    const unsigned b0 = (unsigned)(int)f1 * 2654435761u;
    const unsigned b1 = ((unsigned)(int)f1 + 1u) * 2654435761u;
    const unsigned c0 = (unsigned)(int)f2v * 805459861u;
    const unsigned c1 = ((unsigned)(int)f2v + 1u) * 805459861u;

    const float wa0 = 1.f - t0, wa1 = t0;
    const float wb0 = 1.f - t1, wb1 = t1;
    const float wc0 = 1.f - t2, wc1 = t2;

    const uint32_t hmv  = P.hm;
    const uint32_t mask = hmv - 1u;
    const uint64_t M    = P.magic;
    const bool     p2   = (P.is_pow2 != 0);   // uniform per kernel

    #pragma unroll
    for (int n = 0; n < 8; ++n) {
        unsigned h = ((n & 1) ? a1 : a0)
                   ^ ((n & 2) ? b1 : b0)
                   ^ ((n & 4) ? c1 : c0);
        if (p2) {
            hi[n] = h & mask;
        } else {
            uint64_t low = M * (uint64_t)h;       // Lemire fastmod_u32, exact
            hi[n] = (uint32_t)(((__uint128_t)low * hmv) >> 64);
        }
        w[n] = (((n & 1) ? wa1 : wa0) * ((n & 2) ? wb1 : wb0))
               * ((n & 4) ? wc1 : wc0);
    }
}

// ONE level per dispatch: all 8 XCDs work the same level; the (read-only)
// table replicates into each XCD's L2 (4MB fits). Per-level dur_us becomes
// visible in rocprof, and total time = sum(levels) not 2*max(levels).
// 2 points per thread, both pipelined: 16 gathers in flight, 1 drain.
__global__ __launch_bounds__(TPB)
void hashgrid_gather1(const float* __restrict__ xall,
                      const float* __restrict__ tb,
                      f2* __restrict__ wrow_all,
                      LevelParams P)
{
    const int tid = threadIdx.x;
    const int p0  = blockIdx.x * (TPB * 2);

    const f2*    tbl = (const f2*)tb;
    const float* xp  = xall + (size_t)p0 * 3;
    f2*          wrow = wrow_all + p0;

    const int piA = tid;
    const int piB = tid + TPB;

    const float xa0 = __builtin_nontemporal_load(&xp[piA * 3 + 0]);
    const float xa1 = __builtin_nontemporal_load(&xp[piA * 3 + 1]);
    const float xa2 = __builtin_nontemporal_load(&xp[piA * 3 + 2]);
    const float xb0 = __builtin_nontemporal_load(&xp[piB * 3 + 0]);
    const float xb1 = __builtin_nontemporal_load(&xp[piB * 3 + 1]);
    const float xb2 = __builtin_nontemporal_load(&xp[piB * 3 + 2]);

    unsigned hA[8]; float wA[8];
    unsigned hB[8]; float wB[8];
    hash_calc(xa0, xa1, xa2, P, hA, wA);
    hash_calc(xb0, xb1, xb2, P, hB, wB);

    f2 eA[8], eB[8];
    #pragma unroll
    for (int n = 0; n < 8; ++n) eA[n] = tbl[hA[n]];
    #pragma unroll
    for (int n = 0; n < 8; ++n) eB[n] = tbl[hB[n]];

    float accA0 = 0.f, accA1 = 0.f, accB0 = 0.f, accB1 = 0.f;
    #pragma unroll
    for (int n = 0; n < 8; ++n) {
        accA0 = fmaf(eA[n].x, wA[n], accA0);
        accA1 = fmaf(eA[n].y, wA[n], accA1);
    }
    #pragma unroll
    for (int n = 0; n < 8; ++n) {
        accB0 = fmaf(eB[n].x, wB[n], accB0);
        accB1 = fmaf(eB[n].y, wB[n], accB1);
    }

    f2 vA; vA.x = accA0; vA.y = accA1;
    f2 vB; vB.x = accB0; vB.y = accB1;
    __builtin_nontemporal_store(vA, &wrow[piA]);
    __builtin_nontemporal_store(vB, &wrow[piB]);
}

// Phase 2: streaming interleave ws (level-major) + x -> row-major out,
// flushed as full float4 lines.
__global__ __launch_bounds__(TPB)
void hashgrid_interleave(const float* __restrict__ x,
                         const float* __restrict__ ws,
                         float* __restrict__ out)
{
    __shared__ float srow[TPB * ROW];
    const int tid = threadIdx.x;
    const int p0  = blockIdx.x * TPB;

    const float* xblk = x + (size_t)p0 * 3;
    #pragma unroll
    for (int j = 0; j < 3; ++j) {
        int idx = tid + j * TPB;
        int p = idx / 3, c = idx - p * 3;
        srow[p * ROW + c] = __builtin_nontemporal_load(&xblk[idx]);
    }
    const f2* wsv = (const f2*)ws;
    #pragma unroll
    for (int l = 0; l < NLEV; ++l) {
        f2 v = __builtin_nontemporal_load(&wsv[(size_t)l * NPTS + p0 + tid]);
        srow[tid * ROW + 3 + 2 * l] = v.x;
        srow[tid * ROW + 4 + 2 * l] = v.y;
    }
    __syncthreads();

    f4*       outv = (f4*)(out + (size_t)p0 * ROW);
    const f4* sv   = (const f4*)srow;
    for (int j = tid; j < (TPB * ROW) / 4; j += TPB)
        __builtin_nontemporal_store(sv[j], &outv[j]);
}

// Fallback (ws too small): direct scattered-store path, level per XCD.
__global__ __launch_bounds__(TPB)
void hashgrid_lvl(const float* __restrict__ x,
                  const float* __restrict__ tables,
                  float* __restrict__ out,
                  LPAll lp, int base)
{
    const int tid = threadIdx.x;
    const int lvl = base + (blockIdx.x & 7);
    const int p0  = (blockIdx.x >> 3) * TPB;

    const float* xp = x + (size_t)p0 * 3;
    const float xv0 = xp[tid * 3 + 0];
    const float xv1 = xp[tid * 3 + 1];
    const float xv2 = xp[tid * 3 + 2];

    const LevelParams P   = lp.lv[lvl];
    const f2*         tbl = (const f2*)(tables + (size_t)lvl * TBL_ENTRIES * 2);

    unsigned hi[8]; float w[8];
    hash_calc(xv0, xv1, xv2, P, hi, w);
    float acc0 = 0.f, acc1 = 0.f;
    #pragma unroll
    for (int n = 0; n < 8; ++n) {
        f2 e = tbl[hi[n]];
        acc0 = fmaf(e.x, w[n], acc0);
        acc1 = fmaf(e.y, w[n], acc1);
    }

    float* orow = out + (size_t)(p0 + tid) * ROW;
    __builtin_nontemporal_store(acc0, &orow[3 + 2 * lvl]);
    __builtin_nontemporal_store(acc1, &orow[4 + 2 * lvl]);
    if (lvl == 0) {
        __builtin_nontemporal_store(xv0, &orow[0]);
        __builtin_nontemporal_store(xv1, &orow[1]);
        __builtin_nontemporal_store(xv2, &orow[2]);
    }
}

extern "C" void kernel_launch(void* const* d_in, const int* in_sizes, int n_in,
                              void* d_out, int out_size, void* d_ws, size_t ws_size,
                              hipStream_t stream)
{
    const float* x      = (const float*)d_in[0];
    const float* tables = (const float*)d_in[1];
    float*       out    = (float*)d_out;

    // Host-side level params with system libm -> bit-identical to CPython math.
    LPAll lp;
    const double beta = exp((log(2048.0) - log(16.0)) / 15.0);
    for (int i = 0; i < NLEV; ++i) {
        double r = floor(16.0 * pow(beta, (double)i));
        double h3 = r * r * r;                 // res^3, exact in double
        uint32_t hm = (h3 < (double)(1u << 19)) ? (uint32_t)h3 : (1u << 19);
        lp.lv[i].resf    = (float)r;
        lp.lv[i].hm      = hm;
        lp.lv[i].is_pow2 = ((hm & (hm - 1u)) == 0u) ? 1u : 0u;
        lp.lv[i].pad     = 0;
        lp.lv[i].magic   = lp.lv[i].is_pow2 ? 0ull : (~0ull / hm + 1ull);
    }

    const size_t ws_need = (size_t)NLEV * NPTS * 2 * sizeof(float);  // 128 MB
    if (ws_size >= ws_need) {
        const int gblocks = NPTS / (TPB * 2);     // 2048 blocks per level
        for (int l = 0; l < NLEV; ++l) {
            hashgrid_gather1<<<gblocks, TPB, 0, stream>>>(
                x,
                tables + (size_t)l * TBL_ENTRIES * 2,
                (f2*)d_ws + (size_t)l * NPTS,
                lp.lv[l]);
        }
        hashgrid_interleave<<<NPTS / TPB, TPB, 0, stream>>>(x, (const float*)d_ws, out);
    } else {
        const int nblocks = 8 * (NPTS / TPB);
        hashgrid_lvl<<<nblocks, TPB, 0, stream>>>(x, tables, out, lp, 0);
        hashgrid_lvl<<<nblocks, TPB, 0, stream>>>(x, tables, out, lp, 8);
    }
}

// Round 11
// 401.943 us; speedup vs baseline: 1.3660x; 1.0913x over previous
//
#include <hip/hip_runtime.h>
#include <math.h>
#include <stdint.h>

#define NPTS   1048576
#define NLEV   16
#define NBIG   11                  // levels 5..15 go through ws
#define TPB    256
#define ROW    35                  // 3 (x) + 16 levels * 2 feats
#define TBL_ENTRIES (1u << 19)

typedef float f4 __attribute__((ext_vector_type(4)));
typedef float f2 __attribute__((ext_vector_type(2)));

struct LevelParams {
    float    resf;
    uint32_t hm;
    uint32_t is_pow2;
    uint32_t pad;
    uint64_t magic;      // Lemire fastmod: ~0ull/hm + 1 (unused when pow2)
};
struct LPAll { LevelParams lv[NLEV]; };

// Compute the 8 hash indices + weights for one point (no loads).
__device__ __forceinline__ void hash_calc(
    float xv0, float xv1, float xv2, const LevelParams& P,
    unsigned (&hi)[8], float (&w)[8])
{
    const float xs0 = xv0 * P.resf, xs1 = xv1 * P.resf, xs2 = xv2 * P.resf;
    const float f0 = floorf(xs0), f1 = floorf(xs1), f2v = floorf(xs2);
    const float t0 = xs0 - f0, t1 = xs1 - f1, t2 = xs2 - f2v;

    const unsigned a0 = (unsigned)(int)f0;
    const unsigned a1 = a0 + 1u;
    const unsigned b0 = (unsigned)(int)f1 * 2654435761u;
    const unsigned b1 = ((unsigned)(int)f1 + 1u) * 2654435761u;
    const unsigned c0 = (unsigned)(int)f2v * 805459861u;
    const unsigned c1 = ((unsigned)(int)f2v + 1u) * 805459861u;

    const float wa0 = 1.f - t0, wa1 = t0;
    const float wb0 = 1.f - t1, wb1 = t1;
    const float wc0 = 1.f - t2, wc1 = t2;

    const uint32_t hmv  = P.hm;
    const uint32_t mask = hmv - 1u;
    const uint64_t M    = P.magic;
    const bool     p2   = (P.is_pow2 != 0);   // uniform per kernel

    #pragma unroll
    for (int n = 0; n < 8; ++n) {
        unsigned h = ((n & 1) ? a1 : a0)
                   ^ ((n & 2) ? b1 : b0)
                   ^ ((n & 4) ? c1 : c0);
        if (p2) {
            hi[n] = h & mask;
        } else {
            uint64_t low = M * (uint64_t)h;       // Lemire fastmod_u32, exact
            hi[n] = (uint32_t)(((__uint128_t)low * hmv) >> 64);
        }
        w[n] = (((n & 1) ? wa1 : wa0) * ((n & 2) ? wb1 : wb0))
               * ((n & 4) ? wc1 : wc0);
    }
}

// Big levels (5..15), ONE level per dispatch: all 8 XCDs on one level; the
// read-only table replicates into each XCD's L2. 2 points per thread,
// pipelined: 16 gathers in flight, 1 drain per pair.  (R9/R10 proven.)
__global__ __launch_bounds__(TPB)
void hashgrid_gather1(const float* __restrict__ xall,
                      const float* __restrict__ tb,
                      f2* __restrict__ wrow_all,
                      LevelParams P)
{
    const int tid = threadIdx.x;
    const int p0  = blockIdx.x * (TPB * 2);

    const f2*    tbl = (const f2*)tb;
    const float* xp  = xall + (size_t)p0 * 3;
    f2*          wrow = wrow_all + p0;

    const int piA = tid;
    const int piB = tid + TPB;

    const float xa0 = __builtin_nontemporal_load(&xp[piA * 3 + 0]);
    const float xa1 = __builtin_nontemporal_load(&xp[piA * 3 + 1]);
    const float xa2 = __builtin_nontemporal_load(&xp[piA * 3 + 2]);
    const float xb0 = __builtin_nontemporal_load(&xp[piB * 3 + 0]);
    const float xb1 = __builtin_nontemporal_load(&xp[piB * 3 + 1]);
    const float xb2 = __builtin_nontemporal_load(&xp[piB * 3 + 2]);

    unsigned hA[8]; float wA[8];
    unsigned hB[8]; float wB[8];
    hash_calc(xa0, xa1, xa2, P, hA, wA);
    hash_calc(xb0, xb1, xb2, P, hB, wB);

    f2 eA[8], eB[8];
    #pragma unroll
    for (int n = 0; n < 8; ++n) eA[n] = tbl[hA[n]];
    #pragma unroll
    for (int n = 0; n < 8; ++n) eB[n] = tbl[hB[n]];

    float accA0 = 0.f, accA1 = 0.f, accB0 = 0.f, accB1 = 0.f;
    #pragma unroll
    for (int n = 0; n < 8; ++n) {
        accA0 = fmaf(eA[n].x, wA[n], accA0);
        accA1 = fmaf(eA[n].y, wA[n], accA1);
    }
    #pragma unroll
    for (int n = 0; n < 8; ++n) {
        accB0 = fmaf(eB[n].x, wB[n], accB0);
        accB1 = fmaf(eB[n].y, wB[n], accB1);
    }

    f2 vA; vA.x = accA0; vA.y = accA1;
    f2 vB; vB.x = accB0; vB.y = accB1;
    __builtin_nontemporal_store(vA, &wrow[piA]);
    __builtin_nontemporal_store(vB, &wrow[piB]);
}

// Final kernel: compute levels 0..4 in-kernel (tables total 2.5MB -> L2/L1
// resident everywhere; overlaps with the HBM stream), read big-level results
// from ws, assemble rows in LDS, flush as full float4 lines.
__global__ __launch_bounds__(TPB)
void hashgrid_final(const float* __restrict__ x,
                    const float* __restrict__ tables,
                    const float* __restrict__ ws,
                    float* __restrict__ out,
                    LPAll lp)
{
    __shared__ float srow[TPB * ROW];
    const int tid = threadIdx.x;
    const int p0  = blockIdx.x * TPB;
    const int pi  = p0 + tid;

    const float xv0 = __builtin_nontemporal_load(&x[(size_t)pi * 3 + 0]);
    const float xv1 = __builtin_nontemporal_load(&x[(size_t)pi * 3 + 1]);
    const float xv2 = __builtin_nontemporal_load(&x[(size_t)pi * 3 + 2]);

    srow[tid * ROW + 0] = xv0;
    srow[tid * ROW + 1] = xv1;
    srow[tid * ROW + 2] = xv2;

    // big levels from ws (coalesced streaming reads), issued early
    const f2* wsv = (const f2*)ws;
    #pragma unroll
    for (int l = 5; l < NLEV; ++l) {
        f2 v = __builtin_nontemporal_load(&wsv[(size_t)(l - 5) * NPTS + pi]);
        srow[tid * ROW + 3 + 2 * l] = v.x;
        srow[tid * ROW + 4 + 2 * l] = v.y;
    }

    // small levels 0..4, two levels pipelined at a time (16 loads in flight)
    #pragma unroll
    for (int lp2 = 0; lp2 < 4; lp2 += 2) {
        const LevelParams PA = lp.lv[lp2];
        const LevelParams PB = lp.lv[lp2 + 1];
        const f2* tA = (const f2*)(tables + (size_t)lp2 * TBL_ENTRIES * 2);
        const f2* tB = (const f2*)(tables + (size_t)(lp2 + 1) * TBL_ENTRIES * 2);

        unsigned hA[8]; float wA[8];
        unsigned hB[8]; float wB[8];
        hash_calc(xv0, xv1, xv2, PA, hA, wA);
        hash_calc(xv0, xv1, xv2, PB, hB, wB);

        f2 eA[8], eB[8];
        #pragma unroll
        for (int n = 0; n < 8; ++n) eA[n] = tA[hA[n]];
        #pragma unroll
        for (int n = 0; n < 8; ++n) eB[n] = tB[hB[n]];

        float a0 = 0.f, a1 = 0.f, b0 = 0.f, b1 = 0.f;
        #pragma unroll
        for (int n = 0; n < 8; ++n) {
            a0 = fmaf(eA[n].x, wA[n], a0);
            a1 = fmaf(eA[n].y, wA[n], a1);
        }
        #pragma unroll
        for (int n = 0; n < 8; ++n) {
            b0 = fmaf(eB[n].x, wB[n], b0);
            b1 = fmaf(eB[n].y, wB[n], b1);
        }
        srow[tid * ROW + 3 + 2 * lp2]     = a0;
        srow[tid * ROW + 4 + 2 * lp2]     = a1;
        srow[tid * ROW + 3 + 2 * (lp2+1)] = b0;
        srow[tid * ROW + 4 + 2 * (lp2+1)] = b1;
    }
    {   // level 4
        const LevelParams P4 = lp.lv[4];
        const f2* t4 = (const f2*)(tables + (size_t)4 * TBL_ENTRIES * 2);
        unsigned h[8]; float w[8];
        hash_calc(xv0, xv1, xv2, P4, h, w);
        f2 e[8];
        #pragma unroll
        for (int n = 0; n < 8; ++n) e[n] = t4[h[n]];
        float a0 = 0.f, a1 = 0.f;
        #pragma unroll
        for (int n = 0; n < 8; ++n) {
            a0 = fmaf(e[n].x, w[n], a0);
            a1 = fmaf(e[n].y, w[n], a1);
        }
        srow[tid * ROW + 3 + 8] = a0;
        srow[tid * ROW + 4 + 8] = a1;
    }
    __syncthreads();

    f4*       outv = (f4*)(out + (size_t)p0 * ROW);
    const f4* sv   = (const f4*)srow;
    for (int j = tid; j < (TPB * ROW) / 4; j += TPB)
        __builtin_nontemporal_store(sv[j], &outv[j]);
}

// Fallback (ws too small): direct scattered-store path, level per XCD.
__global__ __launch_bounds__(TPB)
void hashgrid_lvl(const float* __restrict__ x,
                  const float* __restrict__ tables,
                  float* __restrict__ out,
                  LPAll lp, int base)
{
    const int tid = threadIdx.x;
    const int lvl = base + (blockIdx.x & 7);
    const int p0  = (blockIdx.x >> 3) * TPB;

    const float* xp = x + (size_t)p0 * 3;
    const float xv0 = xp[tid * 3 + 0];
    const float xv1 = xp[tid * 3 + 1];
    const float xv2 = xp[tid * 3 + 2];

    const LevelParams P   = lp.lv[lvl];
    const f2*         tbl = (const f2*)(tables + (size_t)lvl * TBL_ENTRIES * 2);

    unsigned hi[8]; float w[8];
    hash_calc(xv0, xv1, xv2, P, hi, w);
    float acc0 = 0.f, acc1 = 0.f;
    #pragma unroll
    for (int n = 0; n < 8; ++n) {
        f2 e = tbl[hi[n]];
        acc0 = fmaf(e.x, w[n], acc0);
        acc1 = fmaf(e.y, w[n], acc1);
    }

    float* orow = out + (size_t)(p0 + tid) * ROW;
    __builtin_nontemporal_store(acc0, &orow[3 + 2 * lvl]);
    __builtin_nontemporal_store(acc1, &orow[4 + 2 * lvl]);
    if (lvl == 0) {
        __builtin_nontemporal_store(xv0, &orow[0]);
        __builtin_nontemporal_store(xv1, &orow[1]);
        __builtin_nontemporal_store(xv2, &orow[2]);
    }
}

extern "C" void kernel_launch(void* const* d_in, const int* in_sizes, int n_in,
                              void* d_out, int out_size, void* d_ws, size_t ws_size,
                              hipStream_t stream)
{
    const float* x      = (const float*)d_in[0];
    const float* tables = (const float*)d_in[1];
    float*       out    = (float*)d_out;

    // Host-side level params with system libm -> bit-identical to CPython math.
    LPAll lp;
    const double beta = exp((log(2048.0) - log(16.0)) / 15.0);
    for (int i = 0; i < NLEV; ++i) {
        double r = floor(16.0 * pow(beta, (double)i));
        double h3 = r * r * r;                 // res^3, exact in double
        uint32_t hm = (h3 < (double)(1u << 19)) ? (uint32_t)h3 : (1u << 19);
        lp.lv[i].resf    = (float)r;
        lp.lv[i].hm      = hm;
        lp.lv[i].is_pow2 = ((hm & (hm - 1u)) == 0u) ? 1u : 0u;
        lp.lv[i].pad     = 0;
        lp.lv[i].magic   = lp.lv[i].is_pow2 ? 0ull : (~0ull / hm + 1ull);
    }

    const size_t ws_need = (size_t)NBIG * NPTS * 2 * sizeof(float);  // 88 MB
    if (ws_size >= ws_need) {
        const int gblocks = NPTS / (TPB * 2);     // 2048 blocks per level
        for (int l = 5; l < NLEV; ++l) {
            hashgrid_gather1<<<gblocks, TPB, 0, stream>>>(
                x,
                tables + (size_t)l * TBL_ENTRIES * 2,
                (f2*)d_ws + (size_t)(l - 5) * NPTS,
                lp.lv[l]);
        }
        hashgrid_final<<<NPTS / TPB, TPB, 0, stream>>>(
            x, tables, (const float*)d_ws, out, lp);
    } else {
        const int nblocks = 8 * (NPTS / TPB);
        hashgrid_lvl<<<nblocks, TPB, 0, stream>>>(x, tables, out, lp, 0);
        hashgrid_lvl<<<nblocks, TPB, 0, stream>>>(x, tables, out, lp, 8);
    }
}